// Round 1
// baseline (457.408 us; speedup 1.0000x reference)
//
#include <hip/hip_runtime.h>
#include <math.h>

// ContextCluster fused kernel, fp32, MI355X gfx950.
// Geometry: x[16][96][64][64]; HEADS=8, HEAD_DIM=32; fold 8x8 -> region 8x8
// (N=64 points), M=4 centers (2x2 pool of 4x4 blocks).
// One block per (batch bb, fold f1,f2): 16*64 = 1024 blocks, 256 threads.
// Fully fused: conv(f,v) -> cluster -> dispatch -> output projection, all in LDS.

#define TPB 256

__global__ __launch_bounds__(TPB, 3)
void cc_fused(const float* __restrict__ x,
              const float* __restrict__ Wf, const float* __restrict__ bf,
              const float* __restrict__ Wv, const float* __restrict__ bv,
              const float* __restrict__ Wp, const float* __restrict__ bp,
              const float* __restrict__ salpha, const float* __restrict__ sbeta,
              float* __restrict__ out)
{
    // LDS (pad 65 on [c][n] tiles: stride-1 lane access, conflict-free)
    __shared__ __align__(16) float xs[96*65];    // x tile [k][n]
    __shared__ __align__(16) float fs[32*65];    // f points [c][n] (current head)
    __shared__ __align__(16) float vsh[32*65];   // v points [c][n]
    __shared__ __align__(16) float centT[32*4];  // centers transposed [c][m] (float4/c)
    __shared__ float vcent[4*33];                // value centers [m][c]
    __shared__ float smask[4*64];                // masked sim [m][n]
    __shared__ float aggs[4*33];                 // agg [m][c]
    __shared__ float bsim[64];                   // best sim per point
    __shared__ int   bidx[64];                   // argmax center per point
    __shared__ int   cnt[4];                     // points per center

    const int t    = threadIdx.x;
    const int lane = t & 63;
    const int wid  = __builtin_amdgcn_readfirstlane(t >> 6);  // wave id 0..3, SGPR
    const int blk  = blockIdx.x;
    const int bb   = blk >> 6;        // batch 0..15
    const int fold = blk & 63;
    const int f1   = fold >> 3, f2 = fold & 7;

    const float alpha = salpha[0];
    const float beta  = sbeta[0];

    // ---- stage x tile: xs[k][n], n = w_in*8 + h_in ----
    const float* xb = x + (size_t)bb*96*4096 + (size_t)(f1*8)*64 + f2*8;
    for (int i = t; i < 96*32; i += TPB) {
        int c  = i >> 5;          // input channel 0..95
        int p  = i & 31;          // float2 index; n = 2p
        int wi = p >> 2;          // w_in
        int hp = (p & 3) << 1;    // h_in start (even)
        float2 v2 = *(const float2*)(xb + c*4096 + wi*64 + hp);
        int n0 = wi*8 + hp;
        xs[c*65 + n0]     = v2.x;
        xs[c*65 + n0 + 1] = v2.y;
    }

    // ---- projection accumulators: o = wid*24 + j, n = lane ----
    float pacc[24];
    #pragma unroll
    for (int j = 0; j < 24; ++j) pacc[j] = bp[wid*24 + j];

    // conv role: waves 0,1 -> f channels [0..16),[16..32); waves 2,3 -> v
    const bool  isF   = (wid < 2);
    const int   cbase = (wid & 1) * 16;
    const float* Wsel = isF ? Wf : Wv;
    const float* bsel = isF ? bf : bv;
    float*       dst  = isF ? fs : vsh;

    __syncthreads();

    for (int e = 0; e < 8; ++e) {
        // ---- conv: 16 channels/wave x 1 point/lane; weights via scalar loads ----
        const float* wr = Wsel + (size_t)(e*32 + cbase)*96;
        float acc[16];
        #pragma unroll
        for (int j = 0; j < 16; ++j) acc[j] = bsel[e*32 + cbase + j];
        for (int k = 0; k < 96; ++k) {
            float xv = xs[k*65 + lane];
            #pragma unroll
            for (int j = 0; j < 16; ++j)
                acc[j] = fmaf(wr[j*96 + k], xv, acc[j]);
        }
        #pragma unroll
        for (int j = 0; j < 16; ++j) dst[(cbase + j)*65 + lane] = acc[j];
        __syncthreads();

        // ---- P1: max-pool centers (t<128: f -> centT; t>=128: v -> vcent) ----
        {
            int tt = t & 127;
            int m = tt >> 5, c = tt & 31;
            int pw = m >> 1, ph = m & 1;
            const float* src = (t < 128) ? fs : vsh;
            float mx = -3.402823466e38f;
            #pragma unroll
            for (int a = 0; a < 4; ++a)
                #pragma unroll
                for (int b2 = 0; b2 < 4; ++b2) {
                    int n = (pw*4 + a)*8 + ph*4 + b2;
                    mx = fmaxf(mx, src[c*65 + n]);
                }
            if (t < 128) centT[c*4 + m]  = mx;
            else         vcent[m*33 + c] = mx;
            if (t < 4) cnt[t] = 0;
        }
        __syncthreads();

        // ---- P2: cosine sims, sigmoid, argmax (one wave) ----
        if (t < 64) {
            int n = t;
            float d0=0.f,d1=0.f,d2=0.f,d3=0.f;
            float c0=0.f,c1=0.f,c2=0.f,c3=0.f,pn=0.f;
            for (int c = 0; c < 32; ++c) {
                float f = fs[c*65 + n];
                float4 cv = *(const float4*)&centT[c*4];
                d0 = fmaf(cv.x, f, d0); d1 = fmaf(cv.y, f, d1);
                d2 = fmaf(cv.z, f, d2); d3 = fmaf(cv.w, f, d3);
                c0 = fmaf(cv.x, cv.x, c0); c1 = fmaf(cv.y, cv.y, c1);
                c2 = fmaf(cv.z, cv.z, c2); c3 = fmaf(cv.w, cv.w, c3);
                pn = fmaf(f, f, pn);
            }
            float ipn = 1.f / fmaxf(sqrtf(pn), 1e-12f);
            float z0 = beta + alpha * (d0 * (1.f/fmaxf(sqrtf(c0),1e-12f)) * ipn);
            float z1 = beta + alpha * (d1 * (1.f/fmaxf(sqrtf(c1),1e-12f)) * ipn);
            float z2 = beta + alpha * (d2 * (1.f/fmaxf(sqrtf(c2),1e-12f)) * ipn);
            float z3 = beta + alpha * (d3 * (1.f/fmaxf(sqrtf(c3),1e-12f)) * ipn);
            float s0 = 1.f/(1.f + expf(-z0));
            float s1 = 1.f/(1.f + expf(-z1));
            float s2 = 1.f/(1.f + expf(-z2));
            float s3 = 1.f/(1.f + expf(-z3));
            int bi = 0; float bv2 = s0;                 // first-max tie-break
            if (s1 > bv2) { bv2 = s1; bi = 1; }
            if (s2 > bv2) { bv2 = s2; bi = 2; }
            if (s3 > bv2) { bv2 = s3; bi = 3; }
            bidx[n] = bi; bsim[n] = bv2;
            smask[0*64+n] = (bi==0) ? bv2 : 0.f;
            smask[1*64+n] = (bi==1) ? bv2 : 0.f;
            smask[2*64+n] = (bi==2) ? bv2 : 0.f;
            smask[3*64+n] = (bi==3) ? bv2 : 0.f;
            atomicAdd(&cnt[bi], 1);
        }
        __syncthreads();

        // ---- P4: aggregate points -> centers ----
        if (t < 128) {
            int m = t >> 5, c = t & 31;
            float s = 0.f;
            const float* sm = &smask[m*64];
            for (int n2 = 0; n2 < 64; ++n2)
                s = fmaf(vsh[c*65 + n2], sm[n2], s);
            aggs[m*33 + c] = (s + vcent[m*33 + c]) / (float)(cnt[m] + 1);
        }
        __syncthreads();

        // ---- P5: dispatch + fused projection accumulate ----
        {
            float bs = bsim[lane];
            int   bi = bidx[lane];
            float aval[32];
            #pragma unroll
            for (int c = 0; c < 32; ++c) aval[c] = aggs[bi*33 + c] * bs;
            const float* wpr = Wp + (size_t)(wid*24)*256 + e*32;
            #pragma unroll
            for (int j = 0; j < 24; ++j) {
                float s = pacc[j];
                #pragma unroll
                for (int c = 0; c < 32; ++c)
                    s = fmaf(wpr[(size_t)j*256 + c], aval[c], s);
                pacc[j] = s;
            }
        }
        // no barrier needed: next conv writes fs/vsh which P5 does not read;
        // the post-conv barrier orders everything else.
    }

    // ---- store output: out[bb][o][f1*8 + n/8][f2*8 + n%8] ----
    size_t obase = (size_t)bb*96*4096 + (size_t)(f1*8 + (lane >> 3))*64
                 + (size_t)(f2*8) + (lane & 7);
    #pragma unroll
    for (int j = 0; j < 24; ++j)
        out[obase + (size_t)(wid*24 + j)*4096] = pacc[j];
}

extern "C" void kernel_launch(void* const* d_in, const int* in_sizes, int n_in,
                              void* d_out, int out_size, void* d_ws, size_t ws_size,
                              hipStream_t stream) {
    (void)in_sizes; (void)n_in; (void)out_size; (void)d_ws; (void)ws_size;
    cc_fused<<<dim3(1024), dim3(TPB), 0, stream>>>(
        (const float*)d_in[0],  // x
        (const float*)d_in[1],  // Wf
        (const float*)d_in[2],  // bf
        (const float*)d_in[3],  // Wv
        (const float*)d_in[4],  // bv
        (const float*)d_in[5],  // Wp
        (const float*)d_in[6],  // bp
        (const float*)d_in[7],  // sim_alpha
        (const float*)d_in[8],  // sim_beta
        (float*)d_out);
}

// Round 2
// 453.802 us; speedup vs baseline: 1.0079x; 1.0079x over previous
//
#include <hip/hip_runtime.h>
#include <math.h>

// ContextCluster, fp32, MI355X gfx950 — two-kernel pipeline.
// K1: per (batch, fold-region, head) block: conv(f,v) -> pool -> sim/argmax
//     -> aggregate -> dispatch, writes disp[bb][ch][region][n] to d_ws.
// K2: output projection out = Wp @ disp + bp, per (batch, region) block.
// Geometry: x[16][96][64][64]; 8 heads x 32 ch; 8x8 regions of 8x8 points;
// M=4 centers (2x2 pool of 4x4 blocks).

#define TPB 256

__global__ __launch_bounds__(TPB, 6)
void cc_cluster(const float* __restrict__ x,
                const float* __restrict__ Wf, const float* __restrict__ bf,
                const float* __restrict__ Wv, const float* __restrict__ bv,
                const float* __restrict__ salpha, const float* __restrict__ sbeta,
                float* __restrict__ disp)
{
    // ~20 KB LDS -> 8 blocks/CU (wave-slot limited)
    __shared__ float fs[32*65];                  // f points [c][n]
    __shared__ float vsh[32*65];                 // v points [c][n]
    __shared__ __align__(16) float centT[32*4];  // f centers transposed [c][m]
    __shared__ float vcent[4*33];                // v centers [m][c]
    __shared__ float smask[4*64];                // masked sim [m][n]
    __shared__ float aggs[4*33];                 // agg [m][c]
    __shared__ float bsim[64];
    __shared__ int   bidx[64];
    __shared__ int   cnt[4];

    const int t    = threadIdx.x;
    const int lane = t & 63;
    const int wid  = __builtin_amdgcn_readfirstlane(t >> 6);  // 0..3
    const int blk  = blockIdx.x;
    const int e    = blk & 7;           // head
    const int fold = (blk >> 3) & 63;   // region
    const int bb   = blk >> 9;          // batch
    const int f1   = fold >> 3, f2 = fold & 7;

    // conv roles: waves 0,1 -> f channels [0..16),[16..32); waves 2,3 -> v
    const bool   isF   = (wid < 2);
    const int    cbase = (wid & 1) * 16;
    const float* Wsel  = isF ? Wf : Wv;
    const float* bsel  = isF ? bf : bv;
    float*       dst   = isF ? fs : vsh;

    // x addr for this lane's point: n = (lane>>3)*8 + (lane&7)
    const float* xb = x + (size_t)bb*96*4096 + (size_t)(f1*8 + (lane>>3))*64
                    + f2*8 + (lane & 7);
    const float* wr = Wsel + (size_t)(e*32 + cbase)*96;

    float acc[16];
    #pragma unroll
    for (int j = 0; j < 16; ++j) acc[j] = bsel[e*32 + cbase + j];

    // k chunked by 32: 32 outstanding global loads, then contiguous-weight FMA
    for (int kc = 0; kc < 96; kc += 32) {
        const float* xk = xb + (size_t)kc*4096;
        float xreg[32];
        #pragma unroll
        for (int kk = 0; kk < 32; ++kk) xreg[kk] = xk[(size_t)kk*4096];
        const float* wc = wr + kc;
        #pragma unroll
        for (int j = 0; j < 16; ++j) {
            float s = acc[j];
            #pragma unroll
            for (int kk = 0; kk < 32; ++kk)
                s = fmaf(wc[j*96 + kk], xreg[kk], s);
            acc[j] = s;
        }
    }
    #pragma unroll
    for (int j = 0; j < 16; ++j) dst[(cbase + j)*65 + lane] = acc[j];
    if (t < 4) cnt[t] = 0;
    __syncthreads();

    // ---- P1: max-pool centers (t<128: f -> centT; t>=128: v -> vcent) ----
    if (t < 256) {
        int tt = t & 127;
        int m = tt >> 5, c = tt & 31;
        int pw = m >> 1, ph = m & 1;
        const float* src = (t < 128) ? fs : vsh;
        float mx = -3.402823466e38f;
        #pragma unroll
        for (int a = 0; a < 4; ++a)
            #pragma unroll
            for (int b2 = 0; b2 < 4; ++b2) {
                int n = (pw*4 + a)*8 + ph*4 + b2;
                mx = fmaxf(mx, src[c*65 + n]);
            }
        if (t < 128) centT[c*4 + m]  = mx;
        else         vcent[m*33 + c] = mx;
    }
    __syncthreads();

    // ---- P2: cosine sims, sigmoid, argmax (wave 0) ----
    if (t < 64) {
        const float alpha = salpha[0];
        const float beta  = sbeta[0];
        int n = t;
        float d0=0.f,d1=0.f,d2=0.f,d3=0.f;
        float c0=0.f,c1=0.f,c2=0.f,c3=0.f,pn=0.f;
        #pragma unroll
        for (int c = 0; c < 32; ++c) {
            float f = fs[c*65 + n];
            float4 cv = *(const float4*)&centT[c*4];
            d0 = fmaf(cv.x, f, d0); d1 = fmaf(cv.y, f, d1);
            d2 = fmaf(cv.z, f, d2); d3 = fmaf(cv.w, f, d3);
            c0 = fmaf(cv.x, cv.x, c0); c1 = fmaf(cv.y, cv.y, c1);
            c2 = fmaf(cv.z, cv.z, c2); c3 = fmaf(cv.w, cv.w, c3);
            pn = fmaf(f, f, pn);
        }
        float ipn = 1.f / fmaxf(sqrtf(pn), 1e-12f);
        float z0 = beta + alpha * (d0 * (1.f/fmaxf(sqrtf(c0),1e-12f)) * ipn);
        float z1 = beta + alpha * (d1 * (1.f/fmaxf(sqrtf(c1),1e-12f)) * ipn);
        float z2 = beta + alpha * (d2 * (1.f/fmaxf(sqrtf(c2),1e-12f)) * ipn);
        float z3 = beta + alpha * (d3 * (1.f/fmaxf(sqrtf(c3),1e-12f)) * ipn);
        float s0 = 1.f/(1.f + expf(-z0));
        float s1 = 1.f/(1.f + expf(-z1));
        float s2 = 1.f/(1.f + expf(-z2));
        float s3 = 1.f/(1.f + expf(-z3));
        int bi = 0; float bv2 = s0;                // first-max tie-break
        if (s1 > bv2) { bv2 = s1; bi = 1; }
        if (s2 > bv2) { bv2 = s2; bi = 2; }
        if (s3 > bv2) { bv2 = s3; bi = 3; }
        bidx[n] = bi; bsim[n] = bv2;
        smask[0*64+n] = (bi==0) ? bv2 : 0.f;
        smask[1*64+n] = (bi==1) ? bv2 : 0.f;
        smask[2*64+n] = (bi==2) ? bv2 : 0.f;
        smask[3*64+n] = (bi==3) ? bv2 : 0.f;
        atomicAdd(&cnt[bi], 1);
    }
    __syncthreads();

    // ---- P4: aggregate points -> centers ----
    if (t < 128) {
        int m = t >> 5, c = t & 31;
        float s = 0.f;
        const float* sm = &smask[m*64];
        #pragma unroll 8
        for (int n2 = 0; n2 < 64; ++n2)
            s = fmaf(vsh[c*65 + n2], sm[n2], s);
        aggs[m*33 + c] = (s + vcent[m*33 + c]) / (float)(cnt[m] + 1);
    }
    __syncthreads();

    // ---- P5: dispatch -> disp[bb][e*32+c][fold][n] (region-major, coalesced) ----
    {
        float bs = bsim[lane];
        int   bi = bidx[lane];
        size_t obase = (size_t)bb*256*4096 + (size_t)(e*32)*4096
                     + (size_t)fold*64 + lane;
        #pragma unroll
        for (int j = 0; j < 8; ++j) {
            int c = wid*8 + j;
            disp[obase + (size_t)c*4096] = aggs[bi*33 + c] * bs;
        }
    }
}

// K2: out[bb][o][w][h] = sum_c Wp[o][c] * disp[bb][c][fold][n] + bp[o]
__global__ __launch_bounds__(TPB, 6)
void cc_proj(const float* __restrict__ disp, const float* __restrict__ Wp,
             const float* __restrict__ bp, float* __restrict__ out)
{
    __shared__ float ds[32*65];
    const int t    = threadIdx.x;
    const int lane = t & 63;
    const int wid  = __builtin_amdgcn_readfirstlane(t >> 6);  // 0..3
    const int fold = blockIdx.x & 63;
    const int bb   = blockIdx.x >> 6;
    const int f1   = fold >> 3, f2 = fold & 7;

    const size_t dbase = (size_t)bb*256*4096 + (size_t)fold*64 + lane;

    float acc[24];
    #pragma unroll
    for (int j = 0; j < 24; ++j) acc[j] = bp[wid*24 + j];

    for (int c0 = 0; c0 < 256; c0 += 32) {
        __syncthreads();   // protect previous chunk's LDS reads
        #pragma unroll
        for (int s = 0; s < 8; ++s) {
            int cl = wid*8 + s;
            ds[cl*65 + lane] = disp[dbase + (size_t)(c0 + cl)*4096];
        }
        __syncthreads();
        float dreg[32];
        #pragma unroll
        for (int cl = 0; cl < 32; ++cl) dreg[cl] = ds[cl*65 + lane];
        const float* wpr = Wp + (size_t)(wid*24)*256 + c0;
        #pragma unroll
        for (int j = 0; j < 24; ++j) {
            float s = acc[j];
            #pragma unroll
            for (int cl = 0; cl < 32; ++cl)
                s = fmaf(wpr[(size_t)j*256 + cl], dreg[cl], s);
            acc[j] = s;
        }
    }

    // out pixel: w = f1*8 + n/8, h = f2*8 + n%8
    size_t obase = (size_t)bb*96*4096 + (size_t)(f1*8 + (lane >> 3))*64
                 + f2*8 + (lane & 7);
    #pragma unroll
    for (int j = 0; j < 24; ++j)
        out[obase + (size_t)(wid*24 + j)*4096] = acc[j];
}

extern "C" void kernel_launch(void* const* d_in, const int* in_sizes, int n_in,
                              void* d_out, int out_size, void* d_ws, size_t ws_size,
                              hipStream_t stream) {
    (void)in_sizes; (void)n_in; (void)out_size; (void)ws_size;
    float* disp = (float*)d_ws;   // 16*256*4096 floats = 64 MiB
    cc_cluster<<<dim3(8192), dim3(TPB), 0, stream>>>(
        (const float*)d_in[0],  // x
        (const float*)d_in[1],  // Wf
        (const float*)d_in[2],  // bf
        (const float*)d_in[3],  // Wv
        (const float*)d_in[4],  // bv
        (const float*)d_in[7],  // sim_alpha
        (const float*)d_in[8],  // sim_beta
        disp);
    cc_proj<<<dim3(1024), dim3(TPB), 0, stream>>>(
        disp,
        (const float*)d_in[5],  // Wp
        (const float*)d_in[6],  // bp
        (float*)d_out);
}

// Round 3
// 323.466 us; speedup vs baseline: 1.4141x; 1.4029x over previous
//
#include <hip/hip_runtime.h>
#include <math.h>

// ContextCluster, fp32, MI355X gfx950 — two-kernel pipeline, round 3.
// K1: per (batch, region, head) block: conv(f,v) from LDS-staged x ->
//     pool -> sim/argmax -> aggregate -> dispatch -> disp[bb][ch][region][n].
// K2: out = Wp @ disp + bp, per (batch, region) block, LDS-staged disp chunks.
// Both kernels: inner loops are 1 ds_read_b32 + {16,24} scalar-weight FMAs,
// k-chunked with register prefetch so global latency overlaps FMA issue.

#define TPB 256

__global__ __launch_bounds__(TPB, 5)
void cc_cluster(const float* __restrict__ x,
                const float* __restrict__ Wf, const float* __restrict__ bf,
                const float* __restrict__ Wv, const float* __restrict__ bv,
                const float* __restrict__ salpha, const float* __restrict__ sbeta,
                float* __restrict__ disp)
{
    // ~27.9 KB LDS -> 5 blocks/CU
    __shared__ float xs[32*64];                  // x chunk [c_local][n], stride-1 reads
    __shared__ float fs[32*65];                  // f points [c][n]
    __shared__ float vsh[32*65];                 // v points [c][n]
    __shared__ __align__(16) float centT[32*4];  // f centers transposed [c][m]
    __shared__ float vcent[4*33];                // v centers [m][c]
    __shared__ float smask[4*64];                // masked sim [m][n]
    __shared__ float aggs[4*33];                 // agg [m][c]
    __shared__ float bsim[64];
    __shared__ int   bidx[64];
    __shared__ int   cnt[4];

    const int t    = threadIdx.x;
    const int lane = t & 63;
    const int wid  = __builtin_amdgcn_readfirstlane(t >> 6);  // 0..3
    const int blk  = blockIdx.x;
    const int e    = blk & 7;           // head
    const int fold = (blk >> 3) & 63;   // region
    const int bb   = blk >> 9;          // batch
    const int f1   = fold >> 3, f2 = fold & 7;

    // conv roles: waves 0,1 -> f channels [0..16),[16..32); waves 2,3 -> v
    const bool   isF   = (wid < 2);
    const int    cbase = (wid & 1) * 16;
    const float* Wsel  = isF ? Wf : Wv;
    const float* bsel  = isF ? bf : bv;
    float*       dst   = isF ? fs : vsh;

    // staging role: thread t loads channel (kc + (t>>3)), row w=(t&7): 8 floats
    const float* xrow = x + (size_t)bb*96*4096 + (size_t)(t >> 3)*4096
                      + (size_t)(f1*8 + (t & 7))*64 + f2*8;

    float acc[16];
    #pragma unroll
    for (int j = 0; j < 16; ++j) acc[j] = bsel[e*32 + cbase + j];

    // prefetch chunk 0
    float4 pa = *(const float4*)(xrow);
    float4 pb = *(const float4*)(xrow + 4);

    const float* wbase = Wsel + (size_t)(e*32 + cbase)*96;

    for (int kc = 0; kc < 96; kc += 32) {
        if (kc) __syncthreads();             // prev chunk fully consumed
        // write prefetched regs -> xs
        float* xw = &xs[(t >> 3)*64 + (t & 7)*8];
        *(float4*)(xw)     = pa;
        *(float4*)(xw + 4) = pb;
        if (kc < 64) {                        // prefetch next chunk
            const float* nx = xrow + (size_t)(kc + 32)*4096;
            pa = *(const float4*)(nx);
            pb = *(const float4*)(nx + 4);
        }
        __syncthreads();                      // xs ready

        const float* wc = wbase + kc;
        #pragma unroll 2
        for (int k = 0; k < 32; ++k) {
            float xv = xs[k*64 + lane];
            #pragma unroll
            for (int j = 0; j < 16; ++j)
                acc[j] = fmaf(wc[j*96 + k], xv, acc[j]);
        }
    }

    #pragma unroll
    for (int j = 0; j < 16; ++j) dst[(cbase + j)*65 + lane] = acc[j];
    if (t < 4) cnt[t] = 0;
    __syncthreads();

    // ---- P1: max-pool centers (t<128: f -> centT; t>=128: v -> vcent) ----
    {
        int tt = t & 127;
        int m = tt >> 5, c = tt & 31;
        int pw = m >> 1, ph = m & 1;
        const float* src = (t < 128) ? fs : vsh;
        float mx = -3.402823466e38f;
        #pragma unroll
        for (int a = 0; a < 4; ++a)
            #pragma unroll
            for (int b2 = 0; b2 < 4; ++b2) {
                int n = (pw*4 + a)*8 + ph*4 + b2;
                mx = fmaxf(mx, src[c*65 + n]);
            }
        if (t < 128) centT[c*4 + m]  = mx;
        else         vcent[m*33 + c] = mx;
    }
    __syncthreads();

    // ---- P2: cosine sims, sigmoid, argmax (wave 0) ----
    if (t < 64) {
        const float alpha = salpha[0];
        const float beta  = sbeta[0];
        int n = t;
        float d0=0.f,d1=0.f,d2=0.f,d3=0.f;
        float c0=0.f,c1=0.f,c2=0.f,c3=0.f,pn=0.f;
        #pragma unroll
        for (int c = 0; c < 32; ++c) {
            float f = fs[c*65 + n];
            float4 cv = *(const float4*)&centT[c*4];
            d0 = fmaf(cv.x, f, d0); d1 = fmaf(cv.y, f, d1);
            d2 = fmaf(cv.z, f, d2); d3 = fmaf(cv.w, f, d3);
            c0 = fmaf(cv.x, cv.x, c0); c1 = fmaf(cv.y, cv.y, c1);
            c2 = fmaf(cv.z, cv.z, c2); c3 = fmaf(cv.w, cv.w, c3);
            pn = fmaf(f, f, pn);
        }
        float ipn = 1.f / fmaxf(sqrtf(pn), 1e-12f);
        float z0 = beta + alpha * (d0 * (1.f/fmaxf(sqrtf(c0),1e-12f)) * ipn);
        float z1 = beta + alpha * (d1 * (1.f/fmaxf(sqrtf(c1),1e-12f)) * ipn);
        float z2 = beta + alpha * (d2 * (1.f/fmaxf(sqrtf(c2),1e-12f)) * ipn);
        float z3 = beta + alpha * (d3 * (1.f/fmaxf(sqrtf(c3),1e-12f)) * ipn);
        float s0 = 1.f/(1.f + expf(-z0));
        float s1 = 1.f/(1.f + expf(-z1));
        float s2 = 1.f/(1.f + expf(-z2));
        float s3 = 1.f/(1.f + expf(-z3));
        int bi = 0; float bv2 = s0;                // first-max tie-break
        if (s1 > bv2) { bv2 = s1; bi = 1; }
        if (s2 > bv2) { bv2 = s2; bi = 2; }
        if (s3 > bv2) { bv2 = s3; bi = 3; }
        bidx[n] = bi; bsim[n] = bv2;
        smask[0*64+n] = (bi==0) ? bv2 : 0.f;
        smask[1*64+n] = (bi==1) ? bv2 : 0.f;
        smask[2*64+n] = (bi==2) ? bv2 : 0.f;
        smask[3*64+n] = (bi==3) ? bv2 : 0.f;
        atomicAdd(&cnt[bi], 1);
    }
    __syncthreads();

    // ---- P4: aggregate points -> centers ----
    if (t < 128) {
        int m = t >> 5, c = t & 31;
        float s = 0.f;
        const float* sm = &smask[m*64];
        #pragma unroll 8
        for (int n2 = 0; n2 < 64; ++n2)
            s = fmaf(vsh[c*65 + n2], sm[n2], s);
        aggs[m*33 + c] = (s + vcent[m*33 + c]) / (float)(cnt[m] + 1);
    }
    __syncthreads();

    // ---- P5: dispatch -> disp[bb][e*32+c][fold][n] (coalesced) ----
    {
        float bs = bsim[lane];
        int   bi = bidx[lane];
        size_t obase = (size_t)bb*256*4096 + (size_t)(e*32)*4096
                     + (size_t)fold*64 + lane;
        #pragma unroll
        for (int j = 0; j < 8; ++j) {
            int c = wid*8 + j;
            disp[obase + (size_t)c*4096] = aggs[bi*33 + c] * bs;
        }
    }
}

// K2: out[bb][o][w][h] = sum_c Wp[o][c] * disp[bb][c][fold][n] + bp[o]
__global__ __launch_bounds__(TPB, 4)
void cc_proj(const float* __restrict__ disp, const float* __restrict__ Wp,
             const float* __restrict__ bp, float* __restrict__ out)
{
    __shared__ float ds[64*64];   // disp chunk [k_local][n], stride-1 reads
    const int t    = threadIdx.x;
    const int lane = t & 63;
    const int wid  = __builtin_amdgcn_readfirstlane(t >> 6);  // 0..3
    const int fold = blockIdx.x & 63;
    const int bb   = blockIdx.x >> 6;
    const int f1   = fold >> 3, f2 = fold & 7;

    // staging role: thread t loads rows (t>>6) + 4*i, col (t&63); 16 per chunk
    const float* dbase = disp + (size_t)bb*256*4096 + (size_t)fold*64 + lane
                       + (size_t)(t >> 6)*4096;

    float acc[24];
    #pragma unroll
    for (int j = 0; j < 24; ++j) acc[j] = bp[wid*24 + j];

    // prefetch chunk 0 (rows 0..63)
    float pre[16];
    #pragma unroll
    for (int i = 0; i < 16; ++i)
        pre[i] = dbase[(size_t)(4*i)*4096];

    for (int c0 = 0; c0 < 256; c0 += 64) {
        if (c0) __syncthreads();              // prev chunk consumed
        #pragma unroll
        for (int i = 0; i < 16; ++i)
            ds[((t >> 6) + 4*i)*64 + lane] = pre[i];
        if (c0 < 192) {
            const float* nx = dbase + (size_t)(c0 + 64)*4096;
            #pragma unroll
            for (int i = 0; i < 16; ++i)
                pre[i] = nx[(size_t)(4*i)*4096];
        }
        __syncthreads();                      // ds ready

        const float* wpr = Wp + (size_t)(wid*24)*256 + c0;
        #pragma unroll 2
        for (int k = 0; k < 64; ++k) {
            float xv = ds[k*64 + lane];
            #pragma unroll
            for (int j = 0; j < 24; ++j)
                acc[j] = fmaf(wpr[(size_t)j*256 + k], xv, acc[j]);
        }
    }

    // out pixel: w = f1*8 + n/8, h = f2*8 + n%8
    size_t obase = (size_t)bb*96*4096 + (size_t)(f1*8 + (lane >> 3))*64
                 + f2*8 + (lane & 7);
    #pragma unroll
    for (int j = 0; j < 24; ++j)
        out[obase + (size_t)(wid*24 + j)*4096] = acc[j];
}

extern "C" void kernel_launch(void* const* d_in, const int* in_sizes, int n_in,
                              void* d_out, int out_size, void* d_ws, size_t ws_size,
                              hipStream_t stream) {
    (void)in_sizes; (void)n_in; (void)out_size; (void)ws_size;
    float* disp = (float*)d_ws;   // 16*256*4096 floats = 64 MiB
    cc_cluster<<<dim3(8192), dim3(TPB), 0, stream>>>(
        (const float*)d_in[0],  // x
        (const float*)d_in[1],  // Wf
        (const float*)d_in[2],  // bf
        (const float*)d_in[3],  // Wv
        (const float*)d_in[4],  // bv
        (const float*)d_in[7],  // sim_alpha
        (const float*)d_in[8],  // sim_beta
        disp);
    cc_proj<<<dim3(1024), dim3(TPB), 0, stream>>>(
        disp,
        (const float*)d_in[5],  // Wp
        (const float*)d_in[6],  // bp
        (float*)d_out);
}

// Round 4
// 296.830 us; speedup vs baseline: 1.5410x; 1.0897x over previous
//
#include <hip/hip_runtime.h>
#include <math.h>

// ContextCluster, fp32, MI355X gfx950 — round 4.
// K1: per (batch, region, head) block. LDS unioned: buf holds x-staging
//     chunks during conv, then fs/vsh after. 19.3 KB -> 8 blocks/CU (100% occ).
//     P2 parallelized across all 4 waves (m=wave, n=lane).
// K2: LDS-free streaming GEMM, 4-deep register pipeline, grid 2048.

#define TPB 256

__global__ __launch_bounds__(TPB, 8)
void cc_cluster(const float* __restrict__ x,
                const float* __restrict__ Wf, const float* __restrict__ bf,
                const float* __restrict__ Wv, const float* __restrict__ bv,
                const float* __restrict__ salpha, const float* __restrict__ sbeta,
                float* __restrict__ disp)
{
    // unioned buffer: staging x chunks (<=64x65) during conv, fs/vsh after.
    __shared__ float buf[64*65];                 // 16.6 KB
    __shared__ __align__(16) float centT[32*4];  // f centers transposed [c][m]
    __shared__ float vcent[4*33];                // v centers [m][c]
    __shared__ float smask[4*64];                // sims then masked sims [m][n]
    __shared__ float aggs[4*33];                 // agg [m][c]
    __shared__ float bsim[64];
    __shared__ int   bidx[64];
    __shared__ int   cnt[4];

    const int t    = threadIdx.x;
    const int lane = t & 63;
    const int wid  = __builtin_amdgcn_readfirstlane(t >> 6);  // 0..3
    const int blk  = blockIdx.x;
    const int e    = blk & 7;           // head
    const int fold = (blk >> 3) & 63;   // region
    const int bb   = blk >> 9;          // batch
    const int f1   = fold >> 3, f2 = fold & 7;

    // conv roles: waves 0,1 -> f channels [0..16),[16..32); waves 2,3 -> v
    const bool   isF   = (wid < 2);
    const int    cbase = (wid & 1) * 16;
    const float* Wsel  = isF ? Wf : Wv;
    const float* bsel  = isF ? bf : bv;

    // ---- stage chunk0: channels 0..63. thread t: ch=t>>2, rows (t&3)*2,+1 ----
    const int sch = t >> 2;
    const int sw  = (t & 3) * 2;
    const float* xrg = x + (size_t)bb*96*4096 + (size_t)sch*4096
                     + (size_t)(f1*8)*64 + f2*8;
    float4 a0 = *(const float4*)(xrg + sw*64);
    float4 a1 = *(const float4*)(xrg + sw*64 + 4);
    float4 b0 = *(const float4*)(xrg + (sw+1)*64);
    float4 b1 = *(const float4*)(xrg + (sw+1)*64 + 4);
    {
        float* w0 = &buf[sch*65 + sw*8];
        w0[0]=a0.x; w0[1]=a0.y; w0[2]=a0.z; w0[3]=a0.w;
        w0[4]=a1.x; w0[5]=a1.y; w0[6]=a1.z; w0[7]=a1.w;
        float* w1 = &buf[sch*65 + (sw+1)*8];
        w1[0]=b0.x; w1[1]=b0.y; w1[2]=b0.z; w1[3]=b0.w;
        w1[4]=b1.x; w1[5]=b1.y; w1[6]=b1.z; w1[7]=b1.w;
    }
    // ---- prefetch chunk1: channels 64..95. thread t: ch=64+(t>>3), row t&7 ----
    const float* xr2 = x + (size_t)bb*96*4096 + (size_t)(64 + (t >> 3))*4096
                     + (size_t)(f1*8 + (t & 7))*64 + f2*8;
    float4 c0 = *(const float4*)(xr2);
    float4 c1 = *(const float4*)(xr2 + 4);

    float acc[16];
    #pragma unroll
    for (int j = 0; j < 16; ++j) acc[j] = bsel[e*32 + cbase + j];
    const float* wr = Wsel + (size_t)(e*32 + cbase)*96;

    __syncthreads();                      // chunk0 ready
    #pragma unroll 2
    for (int k = 0; k < 64; ++k) {
        float xv = buf[k*65 + lane];
        #pragma unroll
        for (int j = 0; j < 16; ++j)
            acc[j] = fmaf(wr[j*96 + k], xv, acc[j]);
    }
    __syncthreads();                      // chunk0 consumed
    {
        float* w2 = &buf[(t >> 3)*65 + (t & 7)*8];
        w2[0]=c0.x; w2[1]=c0.y; w2[2]=c0.z; w2[3]=c0.w;
        w2[4]=c1.x; w2[5]=c1.y; w2[6]=c1.z; w2[7]=c1.w;
    }
    __syncthreads();                      // chunk1 ready
    #pragma unroll 2
    for (int k = 0; k < 32; ++k) {
        float xv = buf[k*65 + lane];
        #pragma unroll
        for (int j = 0; j < 16; ++j)
            acc[j] = fmaf(wr[j*96 + 64 + k], xv, acc[j]);
    }
    __syncthreads();                      // chunk1 consumed; buf now free

    // ---- write f/v points: fs = buf[0..2080), vsh = buf[2080..4160) ----
    {
        float* dst = buf + (isF ? 0 : 2080);
        #pragma unroll
        for (int j = 0; j < 16; ++j) dst[(cbase + j)*65 + lane] = acc[j];
    }
    if (t < 4) cnt[t] = 0;
    __syncthreads();

    // ---- P1: max-pool centers (t<128: f -> centT; t>=128: v -> vcent) ----
    {
        int tt = t & 127;
        int m = tt >> 5, c = tt & 31;
        int pw = m >> 1, ph = m & 1;
        const float* src = (t < 128) ? buf : (buf + 2080);
        float mx = -3.402823466e38f;
        #pragma unroll
        for (int a = 0; a < 4; ++a)
            #pragma unroll
            for (int b2 = 0; b2 < 4; ++b2) {
                int n = (pw*4 + a)*8 + ph*4 + b2;
                mx = fmaxf(mx, src[c*65 + n]);
            }
        if (t < 128) centT[c*4 + m]  = mx;
        else         vcent[m*33 + c] = mx;
    }
    __syncthreads();

    // ---- P2a: sims, all 256 threads: m = wave, n = lane ----
    {
        const int m = wid, n = lane;
        float d = 0.f, pn = 0.f, cn = 0.f;
        #pragma unroll
        for (int c = 0; c < 32; ++c) {
            float fv = buf[c*65 + n];          // fs
            float cm = centT[c*4 + m];         // wave-uniform broadcast
            d  = fmaf(cm, fv, d);
            pn = fmaf(fv, fv, pn);
            cn = fmaf(cm, cm, cn);
        }
        float ip = 1.f / fmaxf(sqrtf(pn), 1e-12f);
        float ic = 1.f / fmaxf(sqrtf(cn), 1e-12f);
        float z  = sbeta[0] + salpha[0] * (d * ic * ip);
        smask[m*64 + n] = 1.f / (1.f + expf(-z));
    }
    __syncthreads();

    // ---- P2b: argmax + mask (wave 0) ----
    if (t < 64) {
        int n = t;
        float s0 = smask[n], s1 = smask[64+n], s2 = smask[128+n], s3 = smask[192+n];
        int bi = 0; float bv2 = s0;            // first-max tie-break
        if (s1 > bv2) { bv2 = s1; bi = 1; }
        if (s2 > bv2) { bv2 = s2; bi = 2; }
        if (s3 > bv2) { bv2 = s3; bi = 3; }
        bidx[n] = bi; bsim[n] = bv2;
        smask[n]       = (bi==0) ? bv2 : 0.f;
        smask[64 + n]  = (bi==1) ? bv2 : 0.f;
        smask[128 + n] = (bi==2) ? bv2 : 0.f;
        smask[192 + n] = (bi==3) ? bv2 : 0.f;
        atomicAdd(&cnt[bi], 1);
    }
    __syncthreads();

    // ---- P4: aggregate points -> centers ----
    if (t < 128) {
        int m = t >> 5, c = t & 31;
        float s = 0.f;
        const float* sm = &smask[m*64];
        const float* vv = buf + 2080;          // vsh
        #pragma unroll 8
        for (int n2 = 0; n2 < 64; ++n2)
            s = fmaf(vv[c*65 + n2], sm[n2], s);
        aggs[m*33 + c] = (s + vcent[m*33 + c]) / (float)(cnt[m] + 1);
    }
    __syncthreads();

    // ---- P5: dispatch -> disp[bb][e*32+c][fold][n] (coalesced) ----
    {
        float bs = bsim[lane];
        int   bi = bidx[lane];
        size_t obase = (size_t)bb*256*4096 + (size_t)(e*32)*4096
                     + (size_t)fold*64 + lane;
        #pragma unroll
        for (int j = 0; j < 8; ++j) {
            int c = wid*8 + j;
            disp[obase + (size_t)c*4096] = aggs[bi*33 + c] * bs;
        }
    }
}

// K2: out[bb][o][w][h] = sum_c Wp[o][c] * disp[bb][c][fold][n] + bp[o]
// LDS-free streaming: lane = point, 4-deep register pipeline, 12 FMA/load.
// grid = 2048: blk = oh*1024 + bb*64 + fold (oh pairs share an XCD -> L2 reuse)
__global__ __launch_bounds__(TPB, 8)
void cc_proj(const float* __restrict__ disp, const float* __restrict__ Wp,
             const float* __restrict__ bp, float* __restrict__ out)
{
    const int t    = threadIdx.x;
    const int lane = t & 63;
    const int wid  = __builtin_amdgcn_readfirstlane(t >> 6);  // 0..3
    const int blk  = blockIdx.x;
    const int oh   = blk >> 10;          // out-channel half 0/1
    const int fold = blk & 63;
    const int bb   = (blk >> 6) & 15;
    const int f1   = fold >> 3, f2 = fold & 7;
    const int och  = oh*48 + wid*12;     // this wave's 12 out channels

    const float* dp  = disp + (size_t)bb*256*4096 + (size_t)fold*64 + lane;
    const float* wpr = Wp + (size_t)och*256;

    float acc[12];
    #pragma unroll
    for (int j = 0; j < 12; ++j) acc[j] = bp[och + j];

    float cur[4], nxt[4];
    #pragma unroll
    for (int i = 0; i < 4; ++i) cur[i] = dp[(size_t)i*4096];

    for (int k0 = 0; k0 < 256; k0 += 4) {
        if (k0 < 252) {
            #pragma unroll
            for (int i = 0; i < 4; ++i)
                nxt[i] = dp[(size_t)(k0 + 4 + i)*4096];
        }
        #pragma unroll
        for (int i = 0; i < 4; ++i) {
            float xv = cur[i];
            #pragma unroll
            for (int j = 0; j < 12; ++j)
                acc[j] = fmaf(wpr[(size_t)j*256 + k0 + i], xv, acc[j]);
        }
        #pragma unroll
        for (int i = 0; i < 4; ++i) cur[i] = nxt[i];
    }

    // out pixel: w = f1*8 + n/8, h = f2*8 + n%8
    size_t obase = (size_t)bb*96*4096 + (size_t)(f1*8 + (lane >> 3))*64
                 + f2*8 + (lane & 7);
    #pragma unroll
    for (int j = 0; j < 12; ++j)
        out[obase + (size_t)(och + j)*4096] = acc[j];
}

extern "C" void kernel_launch(void* const* d_in, const int* in_sizes, int n_in,
                              void* d_out, int out_size, void* d_ws, size_t ws_size,
                              hipStream_t stream) {
    (void)in_sizes; (void)n_in; (void)out_size; (void)ws_size;
    float* disp = (float*)d_ws;   // 16*256*4096 floats = 64 MiB
    cc_cluster<<<dim3(8192), dim3(TPB), 0, stream>>>(
        (const float*)d_in[0],  // x
        (const float*)d_in[1],  // Wf
        (const float*)d_in[2],  // bf
        (const float*)d_in[3],  // Wv
        (const float*)d_in[4],  // bv
        (const float*)d_in[7],  // sim_alpha
        (const float*)d_in[8],  // sim_beta
        disp);
    cc_proj<<<dim3(2048), dim3(TPB), 0, stream>>>(
        disp,
        (const float*)d_in[5],  // Wp
        (const float*)d_in[6],  // bp
        (float*)d_out);
}